// Round 15
// baseline (149.793 us; speedup 1.0000x reference)
//
#include <hip/hip_runtime.h>
#include <hip/hip_bf16.h>
#include <math.h>

typedef short short8 __attribute__((ext_vector_type(8)));
typedef float f32x4 __attribute__((ext_vector_type(4)));
typedef float f32x2 __attribute__((ext_vector_type(2)));

#define QSCALE 0.18033688f  // 0.125 * log2(e), folded into q at projection
#define PKFMA(a, b, c) __builtin_elementwise_fma(a, b, c)

// ---------------------------------------------------------------------------
// helpers: bf16 pack/unpack (RNE), fp8 e4m3 encode/decode, DPP quad reduce
// ---------------------------------------------------------------------------
__device__ __forceinline__ unsigned short pk_bf16(float x) {
    unsigned int b = __float_as_uint(x);
    b += 0x7fffu + ((b >> 16) & 1u);
    return (unsigned short)(b >> 16);
}
__device__ __forceinline__ void unpack8(const uint4 u, float* f) {
    f[0] = __uint_as_float(u.x << 16); f[1] = __uint_as_float(u.x & 0xffff0000u);
    f[2] = __uint_as_float(u.y << 16); f[3] = __uint_as_float(u.y & 0xffff0000u);
    f[4] = __uint_as_float(u.z << 16); f[5] = __uint_as_float(u.z & 0xffff0000u);
    f[6] = __uint_as_float(u.w << 16); f[7] = __uint_as_float(u.w & 0xffff0000u);
}
// bf16x8 -> 4 f32x2 pairs (adjacent channels)
__device__ __forceinline__ void unpack8_v2(const uint4 u, f32x2* f) {
    f[0].x = __uint_as_float(u.x << 16); f[0].y = __uint_as_float(u.x & 0xffff0000u);
    f[1].x = __uint_as_float(u.y << 16); f[1].y = __uint_as_float(u.y & 0xffff0000u);
    f[2].x = __uint_as_float(u.z << 16); f[2].y = __uint_as_float(u.z & 0xffff0000u);
    f[3].x = __uint_as_float(u.w << 16); f[3].y = __uint_as_float(u.w & 0xffff0000u);
}
__device__ __forceinline__ unsigned char enc_fp8(float x) {
    return (unsigned char)(__builtin_amdgcn_cvt_pk_fp8_f32(x, x, 0, false) & 0xff);
}

// ---------------------------------------------------------------------------
// count: per-node in-degree (deg zeroed inside prep_kernel)
// ---------------------------------------------------------------------------
__global__ void count_kernel(const int* __restrict__ dst, int* __restrict__ deg, int E) {
    int e = blockIdx.x * blockDim.x + threadIdx.x;
    if (e < E) atomicAdd(&deg[dst[e]], 1);
}

// ---------------------------------------------------------------------------
// fused scan: each block directly sums all preceding deg entries, then
// LDS-scans its own 1024.
// ---------------------------------------------------------------------------
__global__ __launch_bounds__(1024) void scan_kernel(const int* __restrict__ deg,
                                                    int* __restrict__ offs,
                                                    int* __restrict__ cursor,
                                                    int n, int nb) {
    __shared__ int s[1024];
    const int b = blockIdx.x, t = threadIdx.x;
    int partial = 0;
    for (int i = t; i < b * 1024; i += 1024) partial += deg[i];
    s[t] = partial;
    __syncthreads();
    for (int off = 512; off > 0; off >>= 1) {
        if (t < off) s[t] += s[t + off];
        __syncthreads();
    }
    const int base = s[0];
    __syncthreads();
    const int i = b * 1024 + t;
    const int v = (i < n) ? deg[i] : 0;
    s[t] = v;
    __syncthreads();
    for (int off = 1; off < 1024; off <<= 1) {
        int x = (t >= off) ? s[t - off] : 0;
        __syncthreads();
        s[t] += x;
        __syncthreads();
    }
    if (i < n) {
        const int o = base + s[t] - v;
        offs[i] = o;
        cursor[i] = o;
    }
    if (b == nb - 1 && t == 1023) offs[n] = base + s[1023];
}

// ---------------------------------------------------------------------------
// Weight conversion body: f32 -> bf16 pre-swizzled fragment layout.
// ---------------------------------------------------------------------------
template <int K, int NT, int CFG>
__device__ __forceinline__ void convw_body(const float* Wa, const float* Wb,
                                           const float* Wc, const float* Wd,
                                           unsigned short* out, int t) {
    constexpr int KS = K / 32;
    if (t >= NT * K * 64) return;
    const int jj = t & 7;
    const int lane = (t >> 3) & 63;
    const int nf = (t >> 9) & 3;
    const int rest = t >> 11;
    const int ks = rest % KS;
    const int nt = rest / KS;
    const int k = ks * 32 + (lane >> 4) * 8 + jj;
    const int c64 = nf * 16 + (lane & 15);
    float v;
    if (CFG == 1) {
        const int j = nt >> 2;
        const float* W = (j == 0) ? Wa : (j == 1) ? Wb : (j == 2) ? Wc : Wd;
        v = W[(size_t)k * 256 + (nt & 3) * 64 + c64];
    } else if (CFG == 2) {
        const float* W = (nt == 0) ? Wa : (nt == 1) ? Wb : (nt == 2) ? Wc : Wd;
        v = W[(size_t)k * 64 + c64];
    } else {
        v = Wa[(size_t)k * 64 + c64];
    }
    out[t] = pk_bf16(v);
}

// prep: x->bf16, 3 weight conversions, zero deg — one dispatch.
__global__ __launch_bounds__(256) void prep_kernel(
    const float* __restrict__ x, unsigned short* __restrict__ xb, int nx, int nA,
    const float* __restrict__ W1, unsigned short* __restrict__ wswzL,
    const float* __restrict__ Wq1, const float* __restrict__ Wk1,
    const float* __restrict__ Wv1, const float* __restrict__ Ws1,
    unsigned short* __restrict__ wswz1,
    const float* __restrict__ Wq2, const float* __restrict__ Wk2,
    const float* __restrict__ Wv2, const float* __restrict__ Ws2,
    unsigned short* __restrict__ wswz2,
    int* __restrict__ deg, int ndeg) {
    int b = blockIdx.x;
    if (b < nA) {
        int t = b * 256 + threadIdx.x;
        if (t < nx) xb[t] = pk_bf16(x[t]);
        return;
    }
    b -= nA;
    if (b < 32) { convw_body<128, 1, 0>(W1, W1, W1, W1, wswzL, b * 256 + threadIdx.x); return; }
    b -= 32;
    if (b < 256) { convw_body<64, 16, 1>(Wq1, Wk1, Wv1, Ws1, wswz1, b * 256 + threadIdx.x); return; }
    b -= 256;
    if (b < 256) { convw_body<256, 4, 2>(Wq2, Wk2, Wv2, Ws2, wswz2, b * 256 + threadIdx.x); return; }
    b -= 256;
    {
        int t = b * 256 + threadIdx.x;
        if (t < ndeg) deg[t] = 0;
    }
}

// ---------------------------------------------------------------------------
// MFMA GEMM: C[M x NT*64] = A[M x K](bf16) @ W(bf16, pre-swizzled) + bias.
// KIND 1: conv1 proj -> q bf16 (pre-scaled); kv1 plane [head][node][128B]
//         where 16B chunk c>>3: bytes 0-7 = k[8], 8-15 = v[8] (fp8 split).
// KIND 2: conv2 proj -> q bf16 (pre-scaled), kv block 192B, s f32.
// ---------------------------------------------------------------------------
template <int K, int NT, int KIND>
__global__ __launch_bounds__(256) void mfma_gemm_kernel(
    const unsigned short* __restrict__ A, const unsigned short* __restrict__ Wswz,
    const float* __restrict__ ba, const float* __restrict__ bb,
    const float* __restrict__ bc, const float* __restrict__ bd,
    unsigned short* __restrict__ qout, unsigned char* __restrict__ kvout,
    void* __restrict__ sout, int n) {
    constexpr int KS = K / 32;
    const int nt = blockIdx.x;
    const int w = threadIdx.x >> 6, l = threadIdx.x & 63;
    const int r0 = blockIdx.y * 64 + w * 16;
    const int lrow = l & 15, lk = l >> 4;

    f32x4 acc[4] = {};
    const unsigned short* wp = Wswz + (size_t)nt * KS * 4 * 512 + (size_t)l * 8;
    const unsigned short* ap = A + (size_t)(r0 + lrow) * K + lk * 8;

#pragma unroll
    for (int ks = 0; ks < KS; ++ks) {
        const short8 a = *(const short8*)(ap + ks * 32);
        const short8 b0 = *(const short8*)(wp + (ks * 4 + 0) * 512);
        const short8 b1 = *(const short8*)(wp + (ks * 4 + 1) * 512);
        const short8 b2 = *(const short8*)(wp + (ks * 4 + 2) * 512);
        const short8 b3 = *(const short8*)(wp + (ks * 4 + 3) * 512);
        acc[0] = __builtin_amdgcn_mfma_f32_16x16x32_bf16(a, b0, acc[0], 0, 0, 0);
        acc[1] = __builtin_amdgcn_mfma_f32_16x16x32_bf16(a, b1, acc[1], 0, 0, 0);
        acc[2] = __builtin_amdgcn_mfma_f32_16x16x32_bf16(a, b2, acc[2], 0, 0, 0);
        acc[3] = __builtin_amdgcn_mfma_f32_16x16x32_bf16(a, b3, acc[3], 0, 0, 0);
    }

    // C layout: col = l&15, row = (l>>4)*4 + reg   [verified m89]
    const int colg = l & 15, rowg = l >> 4;
#pragma unroll
    for (int nf = 0; nf < 4; ++nf) {
        const int c64 = nf * 16 + colg;
        float bias;
        if (KIND == 1) {
            const int j = nt >> 2;
            const float* bsel = (j == 0) ? ba : (j == 1) ? bb : (j == 2) ? bc : bd;
            bias = bsel[(nt & 3) * 64 + c64];
        } else {
            const float* bsel = (nt == 0) ? ba : (nt == 1) ? bb : (nt == 2) ? bc : bd;
            bias = bsel[c64];
        }
#pragma unroll
        for (int r = 0; r < 4; ++r) {
            const int row = r0 + rowg * 4 + r;
            if (row >= n) continue;
            const float val = acc[nf][r] + bias;
            if (KIND == 1) {
                const int j = nt >> 2, hd = nt & 3;
                if (j == 0) {
                    qout[(size_t)row * 256 + hd * 64 + c64] = pk_bf16(val * QSCALE);
                } else if (j == 1) {
                    kvout[((size_t)hd * n + row) * 128 + ((c64 >> 3) << 4) + (c64 & 7)] =
                        enc_fp8(val);
                } else if (j == 2) {
                    kvout[((size_t)hd * n + row) * 128 + ((c64 >> 3) << 4) + 8 + (c64 & 7)] =
                        enc_fp8(val);
                } else {
                    ((unsigned short*)sout)[(size_t)row * 256 + hd * 64 + c64] = pk_bf16(val);
                }
            } else {
                if (nt == 0) {
                    qout[(size_t)row * 64 + c64] = pk_bf16(val * QSCALE);
                } else if (nt == 1) {
                    kvout[(size_t)row * 192 + c64] = enc_fp8(val);
                } else if (nt == 2) {
                    *(unsigned short*)(kvout + (size_t)row * 192 + 64 + c64 * 2) = pk_bf16(val);
                } else {
                    ((float*)sout)[(size_t)row * 64 + c64] = val;
                }
            }
        }
    }
}

// ---------------------------------------------------------------------------
// lin GEMM body: h1 = relu(xb @ W1 + b1) -> bf16 (fused with CSR fill).
// ---------------------------------------------------------------------------
__device__ __forceinline__ void lin_body(const unsigned short* __restrict__ A,
                                         const unsigned short* __restrict__ Wswz,
                                         const float* __restrict__ bias,
                                         unsigned short* __restrict__ hout,
                                         int n, int by, int tid) {
    constexpr int K = 128, KS = 4;
    const int w = tid >> 6, l = tid & 63;
    const int r0 = by * 64 + w * 16;
    const int lrow = l & 15, lk = l >> 4;

    f32x4 acc[4] = {};
    const unsigned short* wp = Wswz + (size_t)l * 8;
    const unsigned short* ap = A + (size_t)(r0 + lrow) * K + lk * 8;

#pragma unroll
    for (int ks = 0; ks < KS; ++ks) {
        const short8 a = *(const short8*)(ap + ks * 32);
        const short8 b0 = *(const short8*)(wp + (ks * 4 + 0) * 512);
        const short8 b1 = *(const short8*)(wp + (ks * 4 + 1) * 512);
        const short8 b2 = *(const short8*)(wp + (ks * 4 + 2) * 512);
        const short8 b3 = *(const short8*)(wp + (ks * 4 + 3) * 512);
        acc[0] = __builtin_amdgcn_mfma_f32_16x16x32_bf16(a, b0, acc[0], 0, 0, 0);
        acc[1] = __builtin_amdgcn_mfma_f32_16x16x32_bf16(a, b1, acc[1], 0, 0, 0);
        acc[2] = __builtin_amdgcn_mfma_f32_16x16x32_bf16(a, b2, acc[2], 0, 0, 0);
        acc[3] = __builtin_amdgcn_mfma_f32_16x16x32_bf16(a, b3, acc[3], 0, 0, 0);
    }
    const int colg = l & 15, rowg = l >> 4;
#pragma unroll
    for (int nf = 0; nf < 4; ++nf) {
        const int c64 = nf * 16 + colg;
        const float bias_v = bias[c64];
#pragma unroll
        for (int r = 0; r < 4; ++r) {
            const int row = r0 + rowg * 4 + r;
            if (row >= n) continue;
            hout[(size_t)row * 64 + c64] = pk_bf16(fmaxf(acc[nf][r] + bias_v, 0.f));
        }
    }
}

__global__ __launch_bounds__(256) void fill_lin_kernel(
    const int* __restrict__ src, const int* __restrict__ dst,
    int* __restrict__ cursor, int* __restrict__ csrc, int E, int nfill,
    const unsigned short* __restrict__ xb, const unsigned short* __restrict__ wswzL,
    const float* __restrict__ b1, unsigned short* __restrict__ h1b, int n) {
    if ((int)blockIdx.x < nfill) {
        int e = blockIdx.x * 256 + threadIdx.x;
        if (e < E) {
            int p = atomicAdd(&cursor[dst[e]], 1);
            csrc[p] = src[e];
        }
        return;
    }
    lin_body(xb, wswzL, b1, h1b, n, blockIdx.x - nfill, threadIdx.x);
}

// ---------------------------------------------------------------------------
// conv1 aggregation (HEADS=4), XCD-head-affinity grid; kv1 plane layout
// [head][node][128B: per-16B chunk = 8 fp8 k | 8 fp8 v]. Branch-free loop,
// clamped loads, packed dual-fp32 math (v_pk_fma_f32 via f32x2 vectors):
// dot = 4 pk_fma + add, acc = 4 pk_fma. q pre-scaled at projection.
// ---------------------------------------------------------------------------
__global__ __launch_bounds__(256) void attn4_kernel(
    const unsigned short* __restrict__ q, const unsigned char* __restrict__ kv,
    const unsigned short* __restrict__ s,
    const int* __restrict__ offs, const int* __restrict__ csrc,
    unsigned short* __restrict__ out, int n) {
    const int bid = blockIdx.x;
    const int head = (bid & 7) >> 1;
    const int ng = (bid >> 3) * 2 + (bid & 1);
    const int lane = threadIdx.x & 63;
    const int node = ng * 4 + (threadIdx.x >> 6);
    if (node >= n) return;
    const int g = lane >> 3;
    const int sl = lane & 7;
    const unsigned colbase = (head << 6) + (sl << 3);
    const unsigned char* kvlane = kv + ((size_t)head * n) * 128 + sl * 16;

    f32x2 qv2[4];
    unpack8_v2(*(const uint4*)(q + ((unsigned)node << 8) + colbase), qv2);

    const int e0 = offs[node], e1 = offs[node + 1];
    const int deg = e1 - e0;
    float denom = 0.f;
    f32x2 acc2[4] = {};

    if (deg > 0) {
        const int iters = (deg + 7) >> 3;
        const int elast = e1 - 1;
        int e = e0 + g;
        uint4 uu = *(const uint4*)(kvlane + ((unsigned)csrc[min(e, elast)] << 7));
        for (int it = 1; it < iters; ++it) {
            const int en = e + 8;
            const uint4 uun = *(const uint4*)(kvlane + ((unsigned)csrc[min(en, elast)] << 7));
            f32x2 kf2[4], vf2[4];
            kf2[0] = __builtin_amdgcn_cvt_pk_f32_fp8(uu.x, false);
            kf2[1] = __builtin_amdgcn_cvt_pk_f32_fp8(uu.x, true);
            kf2[2] = __builtin_amdgcn_cvt_pk_f32_fp8(uu.y, false);
            kf2[3] = __builtin_amdgcn_cvt_pk_f32_fp8(uu.y, true);
            vf2[0] = __builtin_amdgcn_cvt_pk_f32_fp8(uu.z, false);
            vf2[1] = __builtin_amdgcn_cvt_pk_f32_fp8(uu.z, true);
            vf2[2] = __builtin_amdgcn_cvt_pk_f32_fp8(uu.w, false);
            vf2[3] = __builtin_amdgcn_cvt_pk_f32_fp8(uu.w, true);
            f32x2 dp = qv2[0] * kf2[0];
            dp = PKFMA(qv2[1], kf2[1], dp);
            dp = PKFMA(qv2[2], kf2[2], dp);
            dp = PKFMA(qv2[3], kf2[3], dp);
            float dot = dp.x + dp.y;
            dot += __int_as_float(__builtin_amdgcn_mov_dpp(__float_as_int(dot), 0xB1, 0xF, 0xF, true));
            dot += __int_as_float(__builtin_amdgcn_mov_dpp(__float_as_int(dot), 0x4E, 0xF, 0xF, true));
            dot += __shfl_xor(dot, 4, 64);
            const float wgt = __builtin_amdgcn_exp2f(dot);
            f32x2 w2; w2.x = wgt; w2.y = wgt;
            acc2[0] = PKFMA(w2, vf2[0], acc2[0]);
            acc2[1] = PKFMA(w2, vf2[1], acc2[1]);
            acc2[2] = PKFMA(w2, vf2[2], acc2[2]);
            acc2[3] = PKFMA(w2, vf2[3], acc2[3]);
            denom += wgt;
            e = en; uu = uun;
        }
        // final batch: group-uniform mask
        f32x2 kf2[4], vf2[4];
        kf2[0] = __builtin_amdgcn_cvt_pk_f32_fp8(uu.x, false);
        kf2[1] = __builtin_amdgcn_cvt_pk_f32_fp8(uu.x, true);
        kf2[2] = __builtin_amdgcn_cvt_pk_f32_fp8(uu.y, false);
        kf2[3] = __builtin_amdgcn_cvt_pk_f32_fp8(uu.y, true);
        vf2[0] = __builtin_amdgcn_cvt_pk_f32_fp8(uu.z, false);
        vf2[1] = __builtin_amdgcn_cvt_pk_f32_fp8(uu.z, true);
        vf2[2] = __builtin_amdgcn_cvt_pk_f32_fp8(uu.w, false);
        vf2[3] = __builtin_amdgcn_cvt_pk_f32_fp8(uu.w, true);
        f32x2 dp = qv2[0] * kf2[0];
        dp = PKFMA(qv2[1], kf2[1], dp);
        dp = PKFMA(qv2[2], kf2[2], dp);
        dp = PKFMA(qv2[3], kf2[3], dp);
        float dot = dp.x + dp.y;
        dot += __int_as_float(__builtin_amdgcn_mov_dpp(__float_as_int(dot), 0xB1, 0xF, 0xF, true));
        dot += __int_as_float(__builtin_amdgcn_mov_dpp(__float_as_int(dot), 0x4E, 0xF, 0xF, true));
        dot += __shfl_xor(dot, 4, 64);
        float wgt = __builtin_amdgcn_exp2f(dot);
        if (e >= e1) wgt = 0.f;
        f32x2 w2; w2.x = wgt; w2.y = wgt;
        acc2[0] = PKFMA(w2, vf2[0], acc2[0]);
        acc2[1] = PKFMA(w2, vf2[1], acc2[1]);
        acc2[2] = PKFMA(w2, vf2[2], acc2[2]);
        acc2[3] = PKFMA(w2, vf2[3], acc2[3]);
        denom += wgt;
    }

    // butterfly sum over groups (lanes 8, 16, 32); vector adds -> v_pk_add_f32
#pragma unroll
    for (int off = 8; off <= 32; off <<= 1) {
        denom += __shfl_xor(denom, off, 64);
#pragma unroll
        for (int j = 0; j < 4; ++j) {
            f32x2 o;
            o.x = __shfl_xor(acc2[j].x, off, 64);
            o.y = __shfl_xor(acc2[j].y, off, 64);
            acc2[j] += o;
        }
    }

    if (g == 0) {
        float sv[8];
        unpack8(*(const uint4*)(s + ((unsigned)node << 8) + colbase), sv);
        const float inv = 1.f / (denom + 1e-16f);
        float a[8] = {acc2[0].x, acc2[0].y, acc2[1].x, acc2[1].y,
                      acc2[2].x, acc2[2].y, acc2[3].x, acc2[3].y};
        uint4 p;
        unsigned r[8];
#pragma unroll
        for (int i = 0; i < 8; ++i) r[i] = pk_bf16(fmaxf(a[i] * inv + sv[i], 0.f));
        p.x = r[0] | (r[1] << 16);
        p.y = r[2] | (r[3] << 16);
        p.z = r[4] | (r[5] << 16);
        p.w = r[6] | (r[7] << 16);
        *(uint4*)(out + ((unsigned)node << 8) + colbase) = p;
    }
}

// ---------------------------------------------------------------------------
// conv2 aggregation (HEADS=1): wave = node (4 nodes per block). Branch-free,
// packed math. kv2 block 192B = [64 fp8 k | 64 bf16 v] (v bf16: feeds d_out).
// ---------------------------------------------------------------------------
__global__ __launch_bounds__(256) void attn1_kernel(
    const unsigned short* __restrict__ q, const unsigned char* __restrict__ kv,
    const float* __restrict__ s,
    const int* __restrict__ offs, const int* __restrict__ csrc,
    float* __restrict__ out, int n) {
    const int w = threadIdx.x >> 6;
    const int lane = threadIdx.x & 63;
    const int g = lane >> 3;
    const int sl = lane & 7;
    const int node = blockIdx.x * 4 + w;
    if (node >= n) return;
    const unsigned koff = sl * 8;
    const unsigned voff = 64 + sl * 16;

    f32x2 qv2[4];
    unpack8_v2(*(const uint4*)(q + ((unsigned)node << 6) + (sl << 3)), qv2);

    const int e0 = offs[node], e1 = offs[node + 1];
    const int deg = e1 - e0;
    float denom = 0.f;
    f32x2 acc2[4] = {};

    if (deg > 0) {
        const int iters = (deg + 7) >> 3;
        const int elast = e1 - 1;
        int e = e0 + g;
        const unsigned char* kvp = kv + (size_t)(unsigned)csrc[min(e, elast)] * 192;
        uint2 ku = *(const uint2*)(kvp + koff);
        uint4 vu = *(const uint4*)(kvp + voff);
        for (int it = 1; it < iters; ++it) {
            const int en = e + 8;
            const unsigned char* kvpn = kv + (size_t)(unsigned)csrc[min(en, elast)] * 192;
            const uint2 kun = *(const uint2*)(kvpn + koff);
            const uint4 vun = *(const uint4*)(kvpn + voff);
            f32x2 kf2[4], vf2[4];
            kf2[0] = __builtin_amdgcn_cvt_pk_f32_fp8(ku.x, false);
            kf2[1] = __builtin_amdgcn_cvt_pk_f32_fp8(ku.x, true);
            kf2[2] = __builtin_amdgcn_cvt_pk_f32_fp8(ku.y, false);
            kf2[3] = __builtin_amdgcn_cvt_pk_f32_fp8(ku.y, true);
            unpack8_v2(vu, vf2);
            f32x2 dp = qv2[0] * kf2[0];
            dp = PKFMA(qv2[1], kf2[1], dp);
            dp = PKFMA(qv2[2], kf2[2], dp);
            dp = PKFMA(qv2[3], kf2[3], dp);
            float dot = dp.x + dp.y;
            dot += __int_as_float(__builtin_amdgcn_mov_dpp(__float_as_int(dot), 0xB1, 0xF, 0xF, true));
            dot += __int_as_float(__builtin_amdgcn_mov_dpp(__float_as_int(dot), 0x4E, 0xF, 0xF, true));
            dot += __shfl_xor(dot, 4, 64);
            const float wgt = __builtin_amdgcn_exp2f(dot);
            f32x2 w2; w2.x = wgt; w2.y = wgt;
            acc2[0] = PKFMA(w2, vf2[0], acc2[0]);
            acc2[1] = PKFMA(w2, vf2[1], acc2[1]);
            acc2[2] = PKFMA(w2, vf2[2], acc2[2]);
            acc2[3] = PKFMA(w2, vf2[3], acc2[3]);
            denom += wgt;
            e = en; ku = kun; vu = vun;
        }
        f32x2 kf2[4], vf2[4];
        kf2[0] = __builtin_amdgcn_cvt_pk_f32_fp8(ku.x, false);
        kf2[1] = __builtin_amdgcn_cvt_pk_f32_fp8(ku.x, true);
        kf2[2] = __builtin_amdgcn_cvt_pk_f32_fp8(ku.y, false);
        kf2[3] = __builtin_amdgcn_cvt_pk_f32_fp8(ku.y, true);
        unpack8_v2(vu, vf2);
        f32x2 dp = qv2[0] * kf2[0];
        dp = PKFMA(qv2[1], kf2[1], dp);
        dp = PKFMA(qv2[2], kf2[2], dp);
        dp = PKFMA(qv2[3], kf2[3], dp);
        float dot = dp.x + dp.y;
        dot += __int_as_float(__builtin_amdgcn_mov_dpp(__float_as_int(dot), 0xB1, 0xF, 0xF, true));
        dot += __int_as_float(__builtin_amdgcn_mov_dpp(__float_as_int(dot), 0x4E, 0xF, 0xF, true));
        dot += __shfl_xor(dot, 4, 64);
        float wgt = __builtin_amdgcn_exp2f(dot);
        if (e >= e1) wgt = 0.f;
        f32x2 w2; w2.x = wgt; w2.y = wgt;
        acc2[0] = PKFMA(w2, vf2[0], acc2[0]);
        acc2[1] = PKFMA(w2, vf2[1], acc2[1]);
        acc2[2] = PKFMA(w2, vf2[2], acc2[2]);
        acc2[3] = PKFMA(w2, vf2[3], acc2[3]);
        denom += wgt;
    }

#pragma unroll
    for (int off = 8; off <= 32; off <<= 1) {
        denom += __shfl_xor(denom, off, 64);
#pragma unroll
        for (int j = 0; j < 4; ++j) {
            f32x2 o;
            o.x = __shfl_xor(acc2[j].x, off, 64);
            o.y = __shfl_xor(acc2[j].y, off, 64);
            acc2[j] += o;
        }
    }

    if (g == 0) {
        const float* sp = s + ((unsigned)node << 6) + (sl << 3);
        const float4 sva = *(const float4*)sp;
        const float4 svb = *(const float4*)(sp + 4);
        const float inv = 1.f / (denom + 1e-16f);
        float4 oa, ob;
        oa.x = acc2[0].x * inv + sva.x; oa.y = acc2[0].y * inv + sva.y;
        oa.z = acc2[1].x * inv + sva.z; oa.w = acc2[1].y * inv + sva.w;
        ob.x = acc2[2].x * inv + svb.x; ob.y = acc2[2].y * inv + svb.y;
        ob.z = acc2[3].x * inv + svb.z; ob.w = acc2[3].y * inv + svb.w;
        float* op = out + ((unsigned)node << 6) + (sl << 3);
        *(float4*)op = oa;
        *(float4*)(op + 4) = ob;
    }
}

// ---------------------------------------------------------------------------
extern "C" void kernel_launch(void* const* d_in, const int* in_sizes, int n_in,
                              void* d_out, int out_size, void* d_ws, size_t ws_size,
                              hipStream_t stream) {
    const float* x   = (const float*)d_in[0];
    const int*   ei  = (const int*)d_in[1];
    const float* W1  = (const float*)d_in[2];
    const float* b1  = (const float*)d_in[3];
    const float* Wq1 = (const float*)d_in[4];  const float* bq1 = (const float*)d_in[5];
    const float* Wk1 = (const float*)d_in[6];  const float* bk1 = (const float*)d_in[7];
    const float* Wv1 = (const float*)d_in[8];  const float* bv1 = (const float*)d_in[9];
    const float* Ws1 = (const float*)d_in[10]; const float* bs1 = (const float*)d_in[11];
    const float* Wq2 = (const float*)d_in[12]; const float* bq2 = (const float*)d_in[13];
    const float* Wk2 = (const float*)d_in[14]; const float* bk2 = (const float*)d_in[15];
    const float* Wv2 = (const float*)d_in[16]; const float* bv2 = (const float*)d_in[17];
    const float* Ws2 = (const float*)d_in[18]; const float* bs2 = (const float*)d_in[19];

    const int N = in_sizes[0] / 128;
    const int E = in_sizes[1] / 2;
    const int* srcv = ei;
    const int* dstv = ei + E;
    const int rowgroups = (N + 63) / 64;
    const int Mpad = rowgroups * 64;
    const int nscan = (N + 1023) / 1024;

    char* p = (char*)d_ws;
    auto alloc = [&](size_t bytes) -> void* {
        void* r = (void*)p;
        p += (bytes + 255) & ~(size_t)255;
        return r;
    };
    unsigned short* xb  = (unsigned short*)alloc((size_t)Mpad * 128 * 2);  // bf16 x
    unsigned short* h1b = (unsigned short*)alloc((size_t)Mpad * 64 * 2);   // bf16 h1
    unsigned short* q1b = (unsigned short*)alloc((size_t)N * 256 * 2);     // bf16 q1 (pre-scaled)
    unsigned char*  kv1 = (unsigned char*)alloc((size_t)N * 4 * 128);      // [head][node][k8|v8 fp8 split]
    unsigned short* s1b = (unsigned short*)alloc((size_t)N * 256 * 2);     // bf16 s1
    unsigned short* h2b = (unsigned short*)alloc((size_t)Mpad * 256 * 2);  // bf16 h2
    unsigned short* q2b = (unsigned short*)alloc((size_t)N * 64 * 2);      // bf16 q2 (pre-scaled)
    unsigned char*  kv2 = (unsigned char*)alloc((size_t)N * 192);
    float* s2 = (float*)alloc((size_t)N * 64 * 4);
    unsigned short* wswzL = (unsigned short*)alloc((size_t)1 * 128 * 64 * 2);
    unsigned short* wswz1 = (unsigned short*)alloc((size_t)16 * 64 * 64 * 2);
    unsigned short* wswz2 = (unsigned short*)alloc((size_t)4 * 256 * 64 * 2);
    int* deg    = (int*)alloc((size_t)N * 4);
    int* offs   = (int*)alloc(((size_t)N + 1) * 4);
    int* cursor = (int*)alloc((size_t)N * 4);
    int* csrc   = (int*)alloc((size_t)E * 4);
    (void)ws_size; (void)n_in; (void)out_size;

    // --- 1. prep: x->bf16 + weight conversions + zero deg ---
    const int nx = N * 128;
    const int nA = (nx + 255) / 256;
    const int nZ = (N + 255) / 256;
    prep_kernel<<<nA + 32 + 256 + 256 + nZ, 256, 0, stream>>>(
        x, xb, nx, nA, W1, wswzL, Wq1, Wk1, Wv1, Ws1, wswz1,
        Wq2, Wk2, Wv2, Ws2, wswz2, deg, N);

    // --- 2. count in-degrees ---
    count_kernel<<<(E + 255) / 256, 256, 0, stream>>>(dstv, deg, E);

    // --- 3. fused scan -> offs/cursor ---
    scan_kernel<<<nscan, 1024, 0, stream>>>(deg, offs, cursor, N, nscan);

    // --- 4. CSR fill + lin GEMM (independent; fused dispatch) ---
    const int nfill = (E + 255) / 256;
    fill_lin_kernel<<<nfill + rowgroups, 256, 0, stream>>>(
        srcv, dstv, cursor, csrc, E, nfill, xb, wswzL, b1, h1b, N);

    // --- 5. conv1 projections: q bf16 (pre-scaled), kv1 split fp8, s bf16 ---
    mfma_gemm_kernel<64, 16, 1><<<dim3(16, rowgroups), 256, 0, stream>>>(
        h1b, wswz1, bq1, bk1, bv1, bs1, q1b, kv1, (void*)s1b, N);

    // --- 6. conv1 aggregation + skip + relu -> bf16 h2 (head-XCD affinity) ---
    const int ngroups = (N + 3) / 4;
    const int npairs = (ngroups + 1) / 2;
    attn4_kernel<<<npairs * 8, 256, 0, stream>>>(q1b, kv1, s1b, offs, csrc, h2b, N);

    // --- 7. conv2 projections ---
    mfma_gemm_kernel<256, 4, 2><<<dim3(4, rowgroups), 256, 0, stream>>>(
        h2b, wswz2, bq2, bk2, bv2, bs2, q2b, kv2, (void*)s2, N);

    // --- 8. conv2 aggregation + skip -> out ---
    attn1_kernel<<<(N + 3) / 4, 256, 0, stream>>>(q2b, kv2, s2, offs, csrc,
                                                  (float*)d_out, N);
}

// Round 16
// 145.228 us; speedup vs baseline: 1.0314x; 1.0314x over previous
//
#include <hip/hip_runtime.h>
#include <hip/hip_bf16.h>
#include <math.h>

typedef short short8 __attribute__((ext_vector_type(8)));
typedef float f32x4 __attribute__((ext_vector_type(4)));
typedef float f32x2 __attribute__((ext_vector_type(2)));

#define QSCALE 0.18033688f  // 0.125 * log2(e), folded into q at projection

// ---------------------------------------------------------------------------
// helpers: bf16 pack/unpack (RNE), fp8 e4m3 encode/decode, DPP quad reduce
// ---------------------------------------------------------------------------
__device__ __forceinline__ unsigned short pk_bf16(float x) {
    unsigned int b = __float_as_uint(x);
    b += 0x7fffu + ((b >> 16) & 1u);
    return (unsigned short)(b >> 16);
}
__device__ __forceinline__ void unpack8(const uint4 u, float* f) {
    f[0] = __uint_as_float(u.x << 16); f[1] = __uint_as_float(u.x & 0xffff0000u);
    f[2] = __uint_as_float(u.y << 16); f[3] = __uint_as_float(u.y & 0xffff0000u);
    f[4] = __uint_as_float(u.z << 16); f[5] = __uint_as_float(u.z & 0xffff0000u);
    f[6] = __uint_as_float(u.w << 16); f[7] = __uint_as_float(u.w & 0xffff0000u);
}
__device__ __forceinline__ unsigned char enc_fp8(float x) {
    return (unsigned char)(__builtin_amdgcn_cvt_pk_fp8_f32(x, x, 0, false) & 0xff);
}
__device__ __forceinline__ void unpack8_fp8(const uint2 u, float* f) {
    f32x2 a = __builtin_amdgcn_cvt_pk_f32_fp8(u.x, false);
    f32x2 b = __builtin_amdgcn_cvt_pk_f32_fp8(u.x, true);
    f32x2 c = __builtin_amdgcn_cvt_pk_f32_fp8(u.y, false);
    f32x2 d = __builtin_amdgcn_cvt_pk_f32_fp8(u.y, true);
    f[0] = a.x; f[1] = a.y; f[2] = b.x; f[3] = b.y;
    f[4] = c.x; f[5] = c.y; f[6] = d.x; f[7] = d.y;
}
// interleaved kv decode: 16B = 8 channels of [k fp8 | v fp8]
__device__ __forceinline__ void unpack_kv8(const uint4 u, float* k, float* v) {
    f32x2 a0 = __builtin_amdgcn_cvt_pk_f32_fp8(u.x, false);
    f32x2 a1 = __builtin_amdgcn_cvt_pk_f32_fp8(u.x, true);
    f32x2 b0 = __builtin_amdgcn_cvt_pk_f32_fp8(u.y, false);
    f32x2 b1 = __builtin_amdgcn_cvt_pk_f32_fp8(u.y, true);
    f32x2 c0 = __builtin_amdgcn_cvt_pk_f32_fp8(u.z, false);
    f32x2 c1 = __builtin_amdgcn_cvt_pk_f32_fp8(u.z, true);
    f32x2 d0 = __builtin_amdgcn_cvt_pk_f32_fp8(u.w, false);
    f32x2 d1 = __builtin_amdgcn_cvt_pk_f32_fp8(u.w, true);
    k[0] = a0.x; v[0] = a0.y; k[1] = a1.x; v[1] = a1.y;
    k[2] = b0.x; v[2] = b0.y; k[3] = b1.x; v[3] = b1.y;
    k[4] = c0.x; v[4] = c0.y; k[5] = c1.x; v[5] = c1.y;
    k[6] = d0.x; v[6] = d0.y; k[7] = d1.x; v[7] = d1.y;
}
// xor1 + xor2 butterfly adds via DPP quad_perm (VALU only, no LDS pipe)
__device__ __forceinline__ float qsum4(float x) {
    x += __int_as_float(__builtin_amdgcn_mov_dpp(__float_as_int(x), 0xB1, 0xF, 0xF, true));
    x += __int_as_float(__builtin_amdgcn_mov_dpp(__float_as_int(x), 0x4E, 0xF, 0xF, true));
    return x;
}

// ---------------------------------------------------------------------------
// count: per-node in-degree (deg zeroed inside prep_kernel)
// ---------------------------------------------------------------------------
__global__ void count_kernel(const int* __restrict__ dst, int* __restrict__ deg, int E) {
    int e = blockIdx.x * blockDim.x + threadIdx.x;
    if (e < E) atomicAdd(&deg[dst[e]], 1);
}

// ---------------------------------------------------------------------------
// fused scan: each block directly sums all preceding deg entries, then
// LDS-scans its own 1024.
// ---------------------------------------------------------------------------
__global__ __launch_bounds__(1024) void scan_kernel(const int* __restrict__ deg,
                                                    int* __restrict__ offs,
                                                    int* __restrict__ cursor,
                                                    int n, int nb) {
    __shared__ int s[1024];
    const int b = blockIdx.x, t = threadIdx.x;
    int partial = 0;
    for (int i = t; i < b * 1024; i += 1024) partial += deg[i];
    s[t] = partial;
    __syncthreads();
    for (int off = 512; off > 0; off >>= 1) {
        if (t < off) s[t] += s[t + off];
        __syncthreads();
    }
    const int base = s[0];
    __syncthreads();
    const int i = b * 1024 + t;
    const int v = (i < n) ? deg[i] : 0;
    s[t] = v;
    __syncthreads();
    for (int off = 1; off < 1024; off <<= 1) {
        int x = (t >= off) ? s[t - off] : 0;
        __syncthreads();
        s[t] += x;
        __syncthreads();
    }
    if (i < n) {
        const int o = base + s[t] - v;
        offs[i] = o;
        cursor[i] = o;
    }
    if (b == nb - 1 && t == 1023) offs[n] = base + s[1023];
}

// ---------------------------------------------------------------------------
// Weight conversion body: f32 -> bf16 pre-swizzled fragment layout.
// ---------------------------------------------------------------------------
template <int K, int NT, int CFG>
__device__ __forceinline__ void convw_body(const float* Wa, const float* Wb,
                                           const float* Wc, const float* Wd,
                                           unsigned short* out, int t) {
    constexpr int KS = K / 32;
    if (t >= NT * K * 64) return;
    const int jj = t & 7;
    const int lane = (t >> 3) & 63;
    const int nf = (t >> 9) & 3;
    const int rest = t >> 11;
    const int ks = rest % KS;
    const int nt = rest / KS;
    const int k = ks * 32 + (lane >> 4) * 8 + jj;
    const int c64 = nf * 16 + (lane & 15);
    float v;
    if (CFG == 1) {
        const int j = nt >> 2;
        const float* W = (j == 0) ? Wa : (j == 1) ? Wb : (j == 2) ? Wc : Wd;
        v = W[(size_t)k * 256 + (nt & 3) * 64 + c64];
    } else if (CFG == 2) {
        const float* W = (nt == 0) ? Wa : (nt == 1) ? Wb : (nt == 2) ? Wc : Wd;
        v = W[(size_t)k * 64 + c64];
    } else {
        v = Wa[(size_t)k * 64 + c64];
    }
    out[t] = pk_bf16(v);
}

// prep: x->bf16, 3 weight conversions, zero deg — one dispatch.
__global__ __launch_bounds__(256) void prep_kernel(
    const float* __restrict__ x, unsigned short* __restrict__ xb, int nx, int nA,
    const float* __restrict__ W1, unsigned short* __restrict__ wswzL,
    const float* __restrict__ Wq1, const float* __restrict__ Wk1,
    const float* __restrict__ Wv1, const float* __restrict__ Ws1,
    unsigned short* __restrict__ wswz1,
    const float* __restrict__ Wq2, const float* __restrict__ Wk2,
    const float* __restrict__ Wv2, const float* __restrict__ Ws2,
    unsigned short* __restrict__ wswz2,
    int* __restrict__ deg, int ndeg) {
    int b = blockIdx.x;
    if (b < nA) {
        int t = b * 256 + threadIdx.x;
        if (t < nx) xb[t] = pk_bf16(x[t]);
        return;
    }
    b -= nA;
    if (b < 32) { convw_body<128, 1, 0>(W1, W1, W1, W1, wswzL, b * 256 + threadIdx.x); return; }
    b -= 32;
    if (b < 256) { convw_body<64, 16, 1>(Wq1, Wk1, Wv1, Ws1, wswz1, b * 256 + threadIdx.x); return; }
    b -= 256;
    if (b < 256) { convw_body<256, 4, 2>(Wq2, Wk2, Wv2, Ws2, wswz2, b * 256 + threadIdx.x); return; }
    b -= 256;
    {
        int t = b * 256 + threadIdx.x;
        if (t < ndeg) deg[t] = 0;
    }
}

// ---------------------------------------------------------------------------
// MFMA GEMM: C[M x NT*64] = A[M x K](bf16) @ W(bf16, pre-swizzled) + bias.
// KIND 1: conv1 proj -> q bf16 (pre-scaled by QSCALE); kv1 plane
//         [head][node][128B interleaved fp8]; s bf16.
// KIND 2: conv2 proj -> q bf16 (pre-scaled), kv block 192B, s f32.
// ---------------------------------------------------------------------------
template <int K, int NT, int KIND>
__global__ __launch_bounds__(256) void mfma_gemm_kernel(
    const unsigned short* __restrict__ A, const unsigned short* __restrict__ Wswz,
    const float* __restrict__ ba, const float* __restrict__ bb,
    const float* __restrict__ bc, const float* __restrict__ bd,
    unsigned short* __restrict__ qout, unsigned char* __restrict__ kvout,
    void* __restrict__ sout, int n) {
    constexpr int KS = K / 32;
    const int nt = blockIdx.x;
    const int w = threadIdx.x >> 6, l = threadIdx.x & 63;
    const int r0 = blockIdx.y * 64 + w * 16;
    const int lrow = l & 15, lk = l >> 4;

    f32x4 acc[4] = {};
    const unsigned short* wp = Wswz + (size_t)nt * KS * 4 * 512 + (size_t)l * 8;
    const unsigned short* ap = A + (size_t)(r0 + lrow) * K + lk * 8;

#pragma unroll
    for (int ks = 0; ks < KS; ++ks) {
        const short8 a = *(const short8*)(ap + ks * 32);
        const short8 b0 = *(const short8*)(wp + (ks * 4 + 0) * 512);
        const short8 b1 = *(const short8*)(wp + (ks * 4 + 1) * 512);
        const short8 b2 = *(const short8*)(wp + (ks * 4 + 2) * 512);
        const short8 b3 = *(const short8*)(wp + (ks * 4 + 3) * 512);
        acc[0] = __builtin_amdgcn_mfma_f32_16x16x32_bf16(a, b0, acc[0], 0, 0, 0);
        acc[1] = __builtin_amdgcn_mfma_f32_16x16x32_bf16(a, b1, acc[1], 0, 0, 0);
        acc[2] = __builtin_amdgcn_mfma_f32_16x16x32_bf16(a, b2, acc[2], 0, 0, 0);
        acc[3] = __builtin_amdgcn_mfma_f32_16x16x32_bf16(a, b3, acc[3], 0, 0, 0);
    }

    // C layout: col = l&15, row = (l>>4)*4 + reg   [verified m89]
    const int colg = l & 15, rowg = l >> 4;
#pragma unroll
    for (int nf = 0; nf < 4; ++nf) {
        const int c64 = nf * 16 + colg;
        float bias;
        if (KIND == 1) {
            const int j = nt >> 2;
            const float* bsel = (j == 0) ? ba : (j == 1) ? bb : (j == 2) ? bc : bd;
            bias = bsel[(nt & 3) * 64 + c64];
        } else {
            const float* bsel = (nt == 0) ? ba : (nt == 1) ? bb : (nt == 2) ? bc : bd;
            bias = bsel[c64];
        }
#pragma unroll
        for (int r = 0; r < 4; ++r) {
            const int row = r0 + rowg * 4 + r;
            if (row >= n) continue;
            const float val = acc[nf][r] + bias;
            if (KIND == 1) {
                const int j = nt >> 2, hd = nt & 3;
                if (j == 0) {
                    qout[(size_t)row * 256 + hd * 64 + c64] = pk_bf16(val * QSCALE);
                } else if (j == 1) {
                    kvout[((size_t)hd * n + row) * 128 + c64 * 2] = enc_fp8(val);
                } else if (j == 2) {
                    kvout[((size_t)hd * n + row) * 128 + c64 * 2 + 1] = enc_fp8(val);
                } else {
                    ((unsigned short*)sout)[(size_t)row * 256 + hd * 64 + c64] = pk_bf16(val);
                }
            } else {
                if (nt == 0) {
                    qout[(size_t)row * 64 + c64] = pk_bf16(val * QSCALE);
                } else if (nt == 1) {
                    kvout[(size_t)row * 192 + c64] = enc_fp8(val);
                } else if (nt == 2) {
                    *(unsigned short*)(kvout + (size_t)row * 192 + 64 + c64 * 2) = pk_bf16(val);
                } else {
                    ((float*)sout)[(size_t)row * 64 + c64] = val;
                }
            }
        }
    }
}

// ---------------------------------------------------------------------------
// lin GEMM body: h1 = relu(xb @ W1 + b1) -> bf16 (fused with CSR fill).
// ---------------------------------------------------------------------------
__device__ __forceinline__ void lin_body(const unsigned short* __restrict__ A,
                                         const unsigned short* __restrict__ Wswz,
                                         const float* __restrict__ bias,
                                         unsigned short* __restrict__ hout,
                                         int n, int by, int tid) {
    constexpr int K = 128, KS = 4;
    const int w = tid >> 6, l = tid & 63;
    const int r0 = by * 64 + w * 16;
    const int lrow = l & 15, lk = l >> 4;

    f32x4 acc[4] = {};
    const unsigned short* wp = Wswz + (size_t)l * 8;
    const unsigned short* ap = A + (size_t)(r0 + lrow) * K + lk * 8;

#pragma unroll
    for (int ks = 0; ks < KS; ++ks) {
        const short8 a = *(const short8*)(ap + ks * 32);
        const short8 b0 = *(const short8*)(wp + (ks * 4 + 0) * 512);
        const short8 b1 = *(const short8*)(wp + (ks * 4 + 1) * 512);
        const short8 b2 = *(const short8*)(wp + (ks * 4 + 2) * 512);
        const short8 b3 = *(const short8*)(wp + (ks * 4 + 3) * 512);
        acc[0] = __builtin_amdgcn_mfma_f32_16x16x32_bf16(a, b0, acc[0], 0, 0, 0);
        acc[1] = __builtin_amdgcn_mfma_f32_16x16x32_bf16(a, b1, acc[1], 0, 0, 0);
        acc[2] = __builtin_amdgcn_mfma_f32_16x16x32_bf16(a, b2, acc[2], 0, 0, 0);
        acc[3] = __builtin_amdgcn_mfma_f32_16x16x32_bf16(a, b3, acc[3], 0, 0, 0);
    }
    const int colg = l & 15, rowg = l >> 4;
#pragma unroll
    for (int nf = 0; nf < 4; ++nf) {
        const int c64 = nf * 16 + colg;
        const float bias_v = bias[c64];
#pragma unroll
        for (int r = 0; r < 4; ++r) {
            const int row = r0 + rowg * 4 + r;
            if (row >= n) continue;
            hout[(size_t)row * 64 + c64] = pk_bf16(fmaxf(acc[nf][r] + bias_v, 0.f));
        }
    }
}

__global__ __launch_bounds__(256) void fill_lin_kernel(
    const int* __restrict__ src, const int* __restrict__ dst,
    int* __restrict__ cursor, int* __restrict__ csrc, int E, int nfill,
    const unsigned short* __restrict__ xb, const unsigned short* __restrict__ wswzL,
    const float* __restrict__ b1, unsigned short* __restrict__ h1b, int n) {
    if ((int)blockIdx.x < nfill) {
        int e = blockIdx.x * 256 + threadIdx.x;
        if (e < E) {
            int p = atomicAdd(&cursor[dst[e]], 1);
            csrc[p] = src[e];
        }
        return;
    }
    lin_body(xb, wswzL, b1, h1b, n, blockIdx.x - nfill, threadIdx.x);
}

// ---------------------------------------------------------------------------
// conv1 aggregation (HEADS=4), XCD-head-affinity grid; kv1 plane layout
// [head][node][128B interleaved fp8 k|v]. Branch-free inner loop: clamped
// unconditional loads (csrc[min(e,elast)]), wave-uniform trip count, single
// group-uniform mask only on the final batch. q pre-scaled at projection.
// ---------------------------------------------------------------------------
__global__ __launch_bounds__(256) void attn4_kernel(
    const unsigned short* __restrict__ q, const unsigned char* __restrict__ kv,
    const unsigned short* __restrict__ s,
    const int* __restrict__ offs, const int* __restrict__ csrc,
    unsigned short* __restrict__ out, int n) {
    const int bid = blockIdx.x;
    const int head = (bid & 7) >> 1;
    const int ng = (bid >> 3) * 2 + (bid & 1);
    const int lane = threadIdx.x & 63;
    const int node = ng * 4 + (threadIdx.x >> 6);
    if (node >= n) return;
    const int g = lane >> 3;
    const int sl = lane & 7;
    const unsigned colbase = (head << 6) + (sl << 3);
    const unsigned char* kvlane = kv + ((size_t)head * n) * 128 + sl * 16;

    float qv[8];
    unpack8(*(const uint4*)(q + ((unsigned)node << 8) + colbase), qv);

    const int e0 = offs[node], e1 = offs[node + 1];
    const int deg = e1 - e0;
    float denom = 0.f;
    float acc[8] = {0.f, 0.f, 0.f, 0.f, 0.f, 0.f, 0.f, 0.f};

    if (deg > 0) {
        const int iters = (deg + 7) >> 3;
        const int elast = e1 - 1;
        int e = e0 + g;
        uint4 uu = *(const uint4*)(kvlane + ((unsigned)csrc[min(e, elast)] << 7));
        for (int it = 1; it < iters; ++it) {
            const int en = e + 8;
            const uint4 uun = *(const uint4*)(kvlane + ((unsigned)csrc[min(en, elast)] << 7));
            float kf[8], vf[8];
            unpack_kv8(uu, kf, vf);
            float dot = qv[0] * kf[0];
#pragma unroll
            for (int i = 1; i < 8; ++i) dot = fmaf(qv[i], kf[i], dot);
            dot = qsum4(dot);
            dot += __shfl_xor(dot, 4, 64);
            const float wgt = __builtin_amdgcn_exp2f(dot);  // all batches < last fully valid
#pragma unroll
            for (int i = 0; i < 8; ++i) acc[i] = fmaf(wgt, vf[i], acc[i]);
            denom += wgt;
            e = en; uu = uun;
        }
        // final batch: mask invalid groups (group-uniform predicate)
        float kf[8], vf[8];
        unpack_kv8(uu, kf, vf);
        float dot = qv[0] * kf[0];
#pragma unroll
        for (int i = 1; i < 8; ++i) dot = fmaf(qv[i], kf[i], dot);
        dot = qsum4(dot);
        dot += __shfl_xor(dot, 4, 64);
        float wgt = __builtin_amdgcn_exp2f(dot);
        if (e >= e1) wgt = 0.f;
#pragma unroll
        for (int i = 0; i < 8; ++i) acc[i] = fmaf(wgt, vf[i], acc[i]);
        denom += wgt;
    }

    // butterfly sum over groups (lanes 8, 16, 32)
#pragma unroll
    for (int off = 8; off <= 32; off <<= 1) {
        denom += __shfl_xor(denom, off, 64);
#pragma unroll
        for (int i = 0; i < 8; ++i) acc[i] += __shfl_xor(acc[i], off, 64);
    }

    if (g == 0) {
        float sv[8];
        unpack8(*(const uint4*)(s + ((unsigned)node << 8) + colbase), sv);
        const float inv = 1.f / (denom + 1e-16f);
        uint4 p;
        unsigned r[8];
#pragma unroll
        for (int i = 0; i < 8; ++i) r[i] = pk_bf16(fmaxf(acc[i] * inv + sv[i], 0.f));
        p.x = r[0] | (r[1] << 16);
        p.y = r[2] | (r[3] << 16);
        p.z = r[4] | (r[5] << 16);
        p.w = r[6] | (r[7] << 16);
        *(uint4*)(out + ((unsigned)node << 8) + colbase) = p;
    }
}

// ---------------------------------------------------------------------------
// conv2 aggregation (HEADS=1): wave = node (4 nodes per block). Same
// branch-free loop. kv2 block 192B = [64 fp8 k | 64 bf16 v].
// ---------------------------------------------------------------------------
__global__ __launch_bounds__(256) void attn1_kernel(
    const unsigned short* __restrict__ q, const unsigned char* __restrict__ kv,
    const float* __restrict__ s,
    const int* __restrict__ offs, const int* __restrict__ csrc,
    float* __restrict__ out, int n) {
    const int w = threadIdx.x >> 6;
    const int lane = threadIdx.x & 63;
    const int g = lane >> 3;
    const int sl = lane & 7;
    const int node = blockIdx.x * 4 + w;
    if (node >= n) return;
    const unsigned koff = sl * 8;
    const unsigned voff = 64 + sl * 16;

    float qv[8];
    unpack8(*(const uint4*)(q + ((unsigned)node << 6) + (sl << 3)), qv);

    const int e0 = offs[node], e1 = offs[node + 1];
    const int deg = e1 - e0;
    float denom = 0.f;
    float acc[8] = {0.f, 0.f, 0.f, 0.f, 0.f, 0.f, 0.f, 0.f};

    if (deg > 0) {
        const int iters = (deg + 7) >> 3;
        const int elast = e1 - 1;
        int e = e0 + g;
        const unsigned char* kvp = kv + (size_t)(unsigned)csrc[min(e, elast)] * 192;
        uint2 ku = *(const uint2*)(kvp + koff);
        uint4 vu = *(const uint4*)(kvp + voff);
        for (int it = 1; it < iters; ++it) {
            const int en = e + 8;
            const unsigned char* kvpn = kv + (size_t)(unsigned)csrc[min(en, elast)] * 192;
            const uint2 kun = *(const uint2*)(kvpn + koff);
            const uint4 vun = *(const uint4*)(kvpn + voff);
            float kf[8], vf[8];
            unpack8_fp8(ku, kf); unpack8(vu, vf);
            float dot = qv[0] * kf[0];
#pragma unroll
            for (int i = 1; i < 8; ++i) dot = fmaf(qv[i], kf[i], dot);
            dot = qsum4(dot);
            dot += __shfl_xor(dot, 4, 64);
            const float wgt = __builtin_amdgcn_exp2f(dot);
#pragma unroll
            for (int i = 0; i < 8; ++i) acc[i] = fmaf(wgt, vf[i], acc[i]);
            denom += wgt;
            e = en; ku = kun; vu = vun;
        }
        float kf[8], vf[8];
        unpack8_fp8(ku, kf); unpack8(vu, vf);
        float dot = qv[0] * kf[0];
#pragma unroll
        for (int i = 1; i < 8; ++i) dot = fmaf(qv[i], kf[i], dot);
        dot = qsum4(dot);
        dot += __shfl_xor(dot, 4, 64);
        float wgt = __builtin_amdgcn_exp2f(dot);
        if (e >= e1) wgt = 0.f;
#pragma unroll
        for (int i = 0; i < 8; ++i) acc[i] = fmaf(wgt, vf[i], acc[i]);
        denom += wgt;
    }

#pragma unroll
    for (int off = 8; off <= 32; off <<= 1) {
        denom += __shfl_xor(denom, off, 64);
#pragma unroll
        for (int i = 0; i < 8; ++i) acc[i] += __shfl_xor(acc[i], off, 64);
    }

    if (g == 0) {
        const float* sp = s + ((unsigned)node << 6) + (sl << 3);
        const float4 sva = *(const float4*)sp;
        const float4 svb = *(const float4*)(sp + 4);
        const float inv = 1.f / (denom + 1e-16f);
        float4 oa, ob;
        oa.x = acc[0] * inv + sva.x; oa.y = acc[1] * inv + sva.y;
        oa.z = acc[2] * inv + sva.z; oa.w = acc[3] * inv + sva.w;
        ob.x = acc[4] * inv + svb.x; ob.y = acc[5] * inv + svb.y;
        ob.z = acc[6] * inv + svb.z; ob.w = acc[7] * inv + svb.w;
        float* op = out + ((unsigned)node << 6) + (sl << 3);
        *(float4*)op = oa;
        *(float4*)(op + 4) = ob;
    }
}

// ---------------------------------------------------------------------------
extern "C" void kernel_launch(void* const* d_in, const int* in_sizes, int n_in,
                              void* d_out, int out_size, void* d_ws, size_t ws_size,
                              hipStream_t stream) {
    const float* x   = (const float*)d_in[0];
    const int*   ei  = (const int*)d_in[1];
    const float* W1  = (const float*)d_in[2];
    const float* b1  = (const float*)d_in[3];
    const float* Wq1 = (const float*)d_in[4];  const float* bq1 = (const float*)d_in[5];
    const float* Wk1 = (const float*)d_in[6];  const float* bk1 = (const float*)d_in[7];
    const float* Wv1 = (const float*)d_in[8];  const float* bv1 = (const float*)d_in[9];
    const float* Ws1 = (const float*)d_in[10]; const float* bs1 = (const float*)d_in[11];
    const float* Wq2 = (const float*)d_in[12]; const float* bq2 = (const float*)d_in[13];
    const float* Wk2 = (const float*)d_in[14]; const float* bk2 = (const float*)d_in[15];
    const float* Wv2 = (const float*)d_in[16]; const float* bv2 = (const float*)d_in[17];
    const float* Ws2 = (const float*)d_in[18]; const float* bs2 = (const float*)d_in[19];

    const int N = in_sizes[0] / 128;
    const int E = in_sizes[1] / 2;
    const int* srcv = ei;
    const int* dstv = ei + E;
    const int rowgroups = (N + 63) / 64;
    const int Mpad = rowgroups * 64;
    const int nscan = (N + 1023) / 1024;

    char* p = (char*)d_ws;
    auto alloc = [&](size_t bytes) -> void* {
        void* r = (void*)p;
        p += (bytes + 255) & ~(size_t)255;
        return r;
    };
    unsigned short* xb  = (unsigned short*)alloc((size_t)Mpad * 128 * 2);  // bf16 x
    unsigned short* h1b = (unsigned short*)alloc((size_t)Mpad * 64 * 2);   // bf16 h1
    unsigned short* q1b = (unsigned short*)alloc((size_t)N * 256 * 2);     // bf16 q1 (pre-scaled)
    unsigned char*  kv1 = (unsigned char*)alloc((size_t)N * 4 * 128);      // [head][node][k|v fp8 interleaved]
    unsigned short* s1b = (unsigned short*)alloc((size_t)N * 256 * 2);     // bf16 s1
    unsigned short* h2b = (unsigned short*)alloc((size_t)Mpad * 256 * 2);  // bf16 h2
    unsigned short* q2b = (unsigned short*)alloc((size_t)N * 64 * 2);      // bf16 q2 (pre-scaled)
    unsigned char*  kv2 = (unsigned char*)alloc((size_t)N * 192);
    float* s2 = (float*)alloc((size_t)N * 64 * 4);
    unsigned short* wswzL = (unsigned short*)alloc((size_t)1 * 128 * 64 * 2);
    unsigned short* wswz1 = (unsigned short*)alloc((size_t)16 * 64 * 64 * 2);
    unsigned short* wswz2 = (unsigned short*)alloc((size_t)4 * 256 * 64 * 2);
    int* deg    = (int*)alloc((size_t)N * 4);
    int* offs   = (int*)alloc(((size_t)N + 1) * 4);
    int* cursor = (int*)alloc((size_t)N * 4);
    int* csrc   = (int*)alloc((size_t)E * 4);
    (void)ws_size; (void)n_in; (void)out_size;

    // --- 1. prep: x->bf16 + weight conversions + zero deg ---
    const int nx = N * 128;
    const int nA = (nx + 255) / 256;
    const int nZ = (N + 255) / 256;
    prep_kernel<<<nA + 32 + 256 + 256 + nZ, 256, 0, stream>>>(
        x, xb, nx, nA, W1, wswzL, Wq1, Wk1, Wv1, Ws1, wswz1,
        Wq2, Wk2, Wv2, Ws2, wswz2, deg, N);

    // --- 2. count in-degrees ---
    count_kernel<<<(E + 255) / 256, 256, 0, stream>>>(dstv, deg, E);

    // --- 3. fused scan -> offs/cursor ---
    scan_kernel<<<nscan, 1024, 0, stream>>>(deg, offs, cursor, N, nscan);

    // --- 4. CSR fill + lin GEMM (independent; fused dispatch) ---
    const int nfill = (E + 255) / 256;
    fill_lin_kernel<<<nfill + rowgroups, 256, 0, stream>>>(
        srcv, dstv, cursor, csrc, E, nfill, xb, wswzL, b1, h1b, N);

    // --- 5. conv1 projections: q bf16 (pre-scaled), kv1 interleaved fp8, s bf16 ---
    mfma_gemm_kernel<64, 16, 1><<<dim3(16, rowgroups), 256, 0, stream>>>(
        h1b, wswz1, bq1, bk1, bv1, bs1, q1b, kv1, (void*)s1b, N);

    // --- 6. conv1 aggregation + skip + relu -> bf16 h2 (head-XCD affinity) ---
    const int ngroups = (N + 3) / 4;
    const int npairs = (ngroups + 1) / 2;
    attn4_kernel<<<npairs * 8, 256, 0, stream>>>(q1b, kv1, s1b, offs, csrc, h2b, N);

    // --- 7. conv2 projections ---
    mfma_gemm_kernel<256, 4, 2><<<dim3(4, rowgroups), 256, 0, stream>>>(
        h2b, wswz2, bq2, bk2, bv2, bs2, q2b, kv2, (void*)s2, N);

    // --- 8. conv2 aggregation + skip -> out ---
    attn1_kernel<<<(N + 3) / 4, 256, 0, stream>>>(q2b, kv2, s2, offs, csrc,
                                                  (float*)d_out, N);
}